// Round 7
// baseline (22037.099 us; speedup 1.0000x reference)
//
#include <hip/hip_runtime.h>
#include <stdint.h>

// CondDecoder: B=256, T=128, V=64, L=128, H=512, E=32, NL=3, IN0=161 (pad 192)
#define BB 256
#define TT 128
#define HH 512
#define G3 1536

typedef __attribute__((ext_vector_type(8))) short bf16x8;
typedef __attribute__((ext_vector_type(4))) float f32x4;

__device__ __forceinline__ unsigned short f2bf(float f){
  unsigned int x = __builtin_bit_cast(unsigned int, f);
  x = x + 0x7fffu + ((x >> 16) & 1u);
  return (unsigned short)(x >> 16);
}
__device__ __forceinline__ float bf2f(unsigned short u){
  unsigned int x = ((unsigned int)u) << 16;
  return __builtin_bit_cast(float, x);
}
__device__ __forceinline__ void gl_lds16(const void* g, void* l){
  __builtin_amdgcn_global_load_lds((const __attribute__((address_space(1))) unsigned int*)g,
                                   (__attribute__((address_space(3))) unsigned int*)l, 16, 0, 0);
}

// ---- prep: convert five [1536][512] f32 weights to bf16 (Whh0..2, Wih1, Wih2)
__global__ __launch_bounds__(256) void kconv5(
    const float* __restrict__ a0, const float* __restrict__ a1, const float* __restrict__ a2,
    const float* __restrict__ a3, const float* __restrict__ a4,
    unsigned short* __restrict__ d0, unsigned short* __restrict__ d1, unsigned short* __restrict__ d2,
    unsigned short* __restrict__ d3, unsigned short* __restrict__ d4){
  int i = blockIdx.x*256 + threadIdx.x;   // grid 3072*256 = 786432 exactly
  d0[i] = f2bf(a0[i]); d1[i] = f2bf(a1[i]); d2[i] = f2bf(a2[i]);
  d3[i] = f2bf(a3[i]); d4[i] = f2bf(a4[i]);
}

// ---- prep: Wih0 pad 161->192 to bf16; fc_W transpose to [512][64] f32
__global__ __launch_bounds__(256) void kmisc(const float* __restrict__ wih0,
    unsigned short* __restrict__ wih0p, const float* __restrict__ fcw,
    float* __restrict__ fcwt){
  int i = blockIdx.x*256 + threadIdx.x;  // grid 1152*256 = 294912
  if (i < 1536*192){
    int n = i / 192, k = i - n*192;
    wih0p[i] = (k < 161) ? f2bf(wih0[n*161 + k]) : (unsigned short)0;
  }
  if (i < 512*64){
    int k = i >> 6, v = i & 63;
    fcwt[i] = fcw[v*512 + k];
  }
}

// ---- prep: build x0 [32768][192] bf16 (latent | shifted-embed | enthalpy | zeros)
__global__ __launch_bounds__(192) void kx0(const float* __restrict__ latent,
    const float* __restrict__ enth, const int* __restrict__ inp,
    const float* __restrict__ emb, unsigned short* __restrict__ x0){
  int c = threadIdx.x;
  #pragma unroll
  for (int mr = 0; mr < 4; ++mr){
    int m = blockIdx.x*4 + mr;       // grid 8192 -> m < 32768
    int b = m >> 7, t = m & 127;
    float v;
    if (c < 128) v = latent[b*128 + c];
    else if (c < 160){
      int tok = (t == 0) ? 0 : inp[b*128 + t - 1];
      v = emb[tok*32 + (c - 128)];
    }
    else if (c == 160) v = enth[b];
    else v = 0.f;
    x0[(size_t)m*192 + c] = f2bf(v);
  }
}

// ---- bf16 MFMA GEMM: C[m][n] = A[m][K] @ Bt[n][K]^T + bias[n]; M=32768 fixed by grid
__global__ __launch_bounds__(256) void kgemm(const unsigned short* __restrict__ A,
    const unsigned short* __restrict__ Bt, const float* __restrict__ bias,
    void* __restrict__ C, int c_bf16, int K){
  __shared__ __align__(16) unsigned short As[128*32];
  __shared__ __align__(16) unsigned short Bs[128*32];
  const int m0 = blockIdx.y*128, n0 = blockIdx.x*128;
  const int wv = threadIdx.x >> 6, lane = threadIdx.x & 63;
  const int woffM = (wv >> 1)*64, woffN = (wv & 1)*64;
  f32x4 acc[4][4] = {};
  for (int k0 = 0; k0 < K; k0 += 32){
    __syncthreads();
    #pragma unroll
    for (int i = 0; i < 4; ++i){
      int e = wv*4 + i;
      int ee = e & 7;
      int row = ee*16 + (lane >> 2);
      if (e < 8) gl_lds16(A  + (size_t)(m0+row)*K + k0 + (lane & 3)*8, (void*)&As[ee*512]);
      else       gl_lds16(Bt + (size_t)(n0+row)*K + k0 + (lane & 3)*8, (void*)&Bs[ee*512]);
    }
    __syncthreads();
    bf16x8 af[4], bf_[4];
    #pragma unroll
    for (int mt = 0; mt < 4; ++mt)
      af[mt] = *(const bf16x8*)&As[(woffM + mt*16 + (lane & 15))*32 + (lane >> 4)*8];
    #pragma unroll
    for (int nt = 0; nt < 4; ++nt)
      bf_[nt] = *(const bf16x8*)&Bs[(woffN + nt*16 + (lane & 15))*32 + (lane >> 4)*8];
    #pragma unroll
    for (int mt = 0; mt < 4; ++mt)
      #pragma unroll
      for (int nt = 0; nt < 4; ++nt)
        acc[mt][nt] = __builtin_amdgcn_mfma_f32_16x16x32_bf16(af[mt], bf_[nt], acc[mt][nt], 0, 0, 0);
  }
  const int col = lane & 15, lq = lane >> 4;
  #pragma unroll
  for (int nt = 0; nt < 4; ++nt){
    float bv = bias[n0 + woffN + nt*16 + col];
    #pragma unroll
    for (int mt = 0; mt < 4; ++mt)
      #pragma unroll
      for (int r = 0; r < 4; ++r){
        int grow = m0 + woffM + mt*16 + lq*4 + r;
        int gcol = n0 + woffN + nt*16 + col;
        float v = acc[mt][nt][r] + bv;
        size_t idx = (size_t)grow*G3 + gcol;
        if (c_bf16) ((unsigned short*)C)[idx] = f2bf(v);
        else        ((float*)C)[idx] = v;
      }
  }
}

// ---- persistent GRU layer: ZERO cross-block communication.
// 8 blocks (one per 32-row group) x 1024 threads (16 waves). Wave w owns h-cols
// w*32..+31 for ALL 3 gates: 96 gate-rows x 512 K of Whh resident in VGPRs
// (384/lane). h double-buffered in LDS (2x32KB, XOR-swizzled); one barrier/step.
// Gates fully in-lane (r/z/n for col j share a lane). acc initialized from gi+bhh.
__global__ __launch_bounds__(1024, 1) void kgru(
    const unsigned short* __restrict__ Wb, const float* __restrict__ bhh,
    const void* __restrict__ gi, int gi_bf16,
    unsigned short* __restrict__ xo_bf, float* __restrict__ xo_f,
    int store_bf, int store_f){
  const int b0 = blockIdx.x * 32;
  const int w = threadIdx.x >> 6, lane = threadIdx.x & 63;
  const int c = lane & 15, lq = lane >> 4;
  __shared__ __align__(16) unsigned short hs[2][32*512];

  // resident weight fragments: wf[g][half][ks]  (B-operand: col=c -> gate-row, k=ks*32+lq*8)
  bf16x8 wf[3][2][16];
  #pragma unroll
  for (int g = 0; g < 3; ++g)
    #pragma unroll
    for (int hf = 0; hf < 2; ++hf){
      const unsigned short* base = Wb + ((size_t)(g*512 + w*32 + hf*16 + c))*512 + lq*8;
      #pragma unroll
      for (int ks = 0; ks < 16; ++ks)
        wf[g][hf][ks] = *(const bf16x8*)(base + ks*32);
    }
  float bias[3][2];
  #pragma unroll
  for (int g = 0; g < 3; ++g)
    #pragma unroll
    for (int hf = 0; hf < 2; ++hf)
      bias[g][hf] = bhh[g*512 + w*32 + hf*16 + c];
  float h_old[2][2][4];
  #pragma unroll
  for (int mt = 0; mt < 2; ++mt)
    #pragma unroll
    for (int hf = 0; hf < 2; ++hf)
      #pragma unroll
      for (int r = 0; r < 4; ++r) h_old[mt][hf][r] = 0.f;

  const float* gif = (const float*)gi;
  const unsigned short* gih = (const unsigned short*)gi;

  f32x4 acc[2][3][2];   // [mt][gate][half] ; C-layout: col=c, row=lq*4+r
  f32x4 gin[2][2];      // n-gate input slice (kept separate for r*(gh_n+bhh_n))

  auto init_acc = [&](int t){
    #pragma unroll
    for (int mt = 0; mt < 2; ++mt)
      #pragma unroll
      for (int r = 0; r < 4; ++r){
        size_t m = (size_t)(b0 + mt*16 + lq*4 + r)*TT + t;
        #pragma unroll
        for (int hf = 0; hf < 2; ++hf){
          size_t base = m*G3 + w*32 + hf*16 + c;
          float vr, vz, vn;
          if (gi_bf16){
            vr = bf2f(gih[base]); vz = bf2f(gih[base + 512]); vn = bf2f(gih[base + 1024]);
          } else {
            vr = gif[base]; vz = gif[base + 512]; vn = gif[base + 1024];
          }
          acc[mt][0][hf][r] = vr + bias[0][hf];
          acc[mt][1][hf][r] = vz + bias[1][hf];
          acc[mt][2][hf][r] = bias[2][hf];
          gin[mt][hf][r] = vn;
        }
      }
  };

  init_acc(0);
  #pragma unroll 1
  for (int t = 0; t < TT; ++t){
    if (t > 0){
      const char* hsr = (const char*)hs[(t - 1) & 1];
      #pragma unroll
      for (int ks = 0; ks < 16; ++ks){
        const int sw = ((ks*4 + lq) ^ (c & 7)) << 4;
        bf16x8 af0 = *(const bf16x8*)(hsr + (c)*1024 + sw);
        bf16x8 af1 = *(const bf16x8*)(hsr + (16 + c)*1024 + sw);
        #pragma unroll
        for (int g = 0; g < 3; ++g)
          #pragma unroll
          for (int hf = 0; hf < 2; ++hf){
            acc[0][g][hf] = __builtin_amdgcn_mfma_f32_16x16x32_bf16(af0, wf[g][hf][ks], acc[0][g][hf], 0, 0, 0);
            acc[1][g][hf] = __builtin_amdgcn_mfma_f32_16x16x32_bf16(af1, wf[g][hf][ks], acc[1][g][hf], 0, 0, 0);
          }
      }
    }
    // gates (in-lane) + publish fused
    char* hsw = (char*)hs[t & 1];
    #pragma unroll
    for (int mt = 0; mt < 2; ++mt)
      #pragma unroll
      for (int hf = 0; hf < 2; ++hf)
        #pragma unroll
        for (int r = 0; r < 4; ++r){
          float rr = 1.f/(1.f + __expf(-acc[mt][0][hf][r]));
          float zz = 1.f/(1.f + __expf(-acc[mt][1][hf][r]));
          float np = gin[mt][hf][r] + rr*acc[mt][2][hf][r];
          float e2 = __expf(2.f*np);
          float nn = 1.f - 2.f/(e2 + 1.f);
          float hn = (1.f - zz)*nn + zz*h_old[mt][hf][r];
          h_old[mt][hf][r] = hn;
          unsigned short hv = f2bf(hn);
          int row = mt*16 + lq*4 + r;
          int j = w*32 + hf*16 + c;
          *(unsigned short*)(hsw + row*1024 + ((((j >> 3) ^ (row & 7))) << 4) + (j & 7)*2) = hv;
          if (store_bf) xo_bf[((size_t)(b0 + row)*TT + t)*512 + j] = hv;
          if (store_f)  xo_f [((size_t)(b0 + row)*TT + t)*512 + j] = hn;
        }
    if (t + 1 < TT) init_acc(t + 1);   // next-step gi loads fly under barrier
    __syncthreads();
  }
}

// ---- final FC in f32 (precision): logits[m][64] = x[m][512] @ fcwt + fc_b
__global__ __launch_bounds__(256) void kfc(const float* __restrict__ x,
    const float* __restrict__ wt, const float* __restrict__ fcb, float* __restrict__ out){
  __shared__ __align__(16) float xs[16*512];
  const int m0 = blockIdx.x*16;   // grid 2048
  for (int c = threadIdx.x; c < 2048; c += 256){
    int row = c >> 7, o = c & 127;
    *(f32x4*)&xs[row*512 + o*4] = *(const f32x4*)(x + (size_t)(m0+row)*512 + o*4);
  }
  __syncthreads();
  const int colv = threadIdx.x & 63, rq = threadIdx.x >> 6;
  float a0 = 0.f, a1 = 0.f, a2 = 0.f, a3 = 0.f;
  const float* x0p = xs + (rq*4 + 0)*512;
  const float* x1p = xs + (rq*4 + 1)*512;
  const float* x2p = xs + (rq*4 + 2)*512;
  const float* x3p = xs + (rq*4 + 3)*512;
  #pragma unroll 8
  for (int k = 0; k < 512; ++k){
    float w = wt[k*64 + colv];
    a0 += w * x0p[k]; a1 += w * x1p[k]; a2 += w * x2p[k]; a3 += w * x3p[k];
  }
  float bv = fcb[colv];
  out[(size_t)(m0 + rq*4 + 0)*64 + colv] = a0 + bv;
  out[(size_t)(m0 + rq*4 + 1)*64 + colv] = a1 + bv;
  out[(size_t)(m0 + rq*4 + 2)*64 + colv] = a2 + bv;
  out[(size_t)(m0 + rq*4 + 3)*64 + colv] = a3 + bv;
}

extern "C" void kernel_launch(void* const* d_in, const int* in_sizes, int n_in,
                              void* d_out, int out_size, void* d_ws, size_t ws_size,
                              hipStream_t stream){
  const float* latent = (const float*)d_in[0];
  const float* enth   = (const float*)d_in[1];
  const int*   inp    = (const int*)d_in[2];
  const float* emb    = (const float*)d_in[3];
  const float* Wih0   = (const float*)d_in[4];
  const float* Whh0   = (const float*)d_in[5];
  const float* bih0   = (const float*)d_in[6];
  const float* bhh0   = (const float*)d_in[7];
  const float* Wih1   = (const float*)d_in[8];
  const float* Whh1   = (const float*)d_in[9];
  const float* bih1   = (const float*)d_in[10];
  const float* bhh1   = (const float*)d_in[11];
  const float* Wih2   = (const float*)d_in[12];
  const float* Whh2   = (const float*)d_in[13];
  const float* bih2   = (const float*)d_in[14];
  const float* bhh2   = (const float*)d_in[15];
  const float* fcW    = (const float*)d_in[16];
  const float* fcb    = (const float*)d_in[17];

  char* ws = (char*)d_ws;
  constexpr size_t OFF_X0   = 4096;
  constexpr size_t OFF_XA   = OFF_X0   + (size_t)32768*192*2;
  constexpr size_t OFF_XB   = OFF_XA   + (size_t)32768*512*2;
  constexpr size_t OFF_X2F  = OFF_XB   + (size_t)32768*512*2;
  constexpr size_t OFF_WHH  = OFF_X2F  + (size_t)32768*512*4;
  constexpr size_t OFF_WIH0 = OFF_WHH  + (size_t)3*1536*512*2;
  constexpr size_t OFF_WIH1 = OFF_WIH0 + (size_t)1536*192*2;
  constexpr size_t OFF_WIH2 = OFF_WIH1 + (size_t)1536*512*2;
  constexpr size_t OFF_FCWT = OFF_WIH2 + (size_t)1536*512*2;
  constexpr size_t OFF_GI   = OFF_FCWT + (size_t)512*64*4;

  unsigned short* x0    = (unsigned short*)(ws + OFF_X0);
  unsigned short* xa    = (unsigned short*)(ws + OFF_XA);
  unsigned short* xb    = (unsigned short*)(ws + OFF_XB);
  float* x2f            = (float*)(ws + OFF_X2F);
  unsigned short* whb0  = (unsigned short*)(ws + OFF_WHH);
  unsigned short* whb1  = whb0 + (size_t)1536*512;
  unsigned short* whb2  = whb1 + (size_t)1536*512;
  unsigned short* wih0p = (unsigned short*)(ws + OFF_WIH0);
  unsigned short* wih1b = (unsigned short*)(ws + OFF_WIH1);
  unsigned short* wih2b = (unsigned short*)(ws + OFF_WIH2);
  float* fcwt           = (float*)(ws + OFF_FCWT);
  void* gi              = (void*)(ws + OFF_GI);
  int gi_bf16 = (ws_size >= OFF_GI + (size_t)32768*1536*4) ? 0 : 1;  // f32 gi if ws permits

  kconv5<<<3072, 256, 0, stream>>>(Whh0, Whh1, Whh2, Wih1, Wih2, whb0, whb1, whb2, wih1b, wih2b);
  kmisc <<<1152, 256, 0, stream>>>(Wih0, wih0p, fcW, fcwt);
  kx0   <<<8192, 192, 0, stream>>>(latent, enth, inp, emb, x0);

  kgemm<<<dim3(12,256), 256, 0, stream>>>(x0, wih0p, bih0, gi, gi_bf16, 192);
  kgru <<<8, 1024, 0, stream>>>(whb0, bhh0, gi, gi_bf16, xa, x2f, 1, 0);
  kgemm<<<dim3(12,256), 256, 0, stream>>>(xa, wih1b, bih1, gi, gi_bf16, 512);
  kgru <<<8, 1024, 0, stream>>>(whb1, bhh1, gi, gi_bf16, xb, x2f, 1, 0);
  kgemm<<<dim3(12,256), 256, 0, stream>>>(xb, wih2b, bih2, gi, gi_bf16, 512);
  kgru <<<8, 1024, 0, stream>>>(whb2, bhh2, gi, gi_bf16, xa, x2f, 0, 1);
  kfc  <<<2048, 256, 0, stream>>>(x2f, fcwt, fcb, (float*)d_out);
}

// Round 8
// 16801.884 us; speedup vs baseline: 1.3116x; 1.3116x over previous
//
#include <hip/hip_runtime.h>
#include <stdint.h>

// CondDecoder: B=256, T=128, V=64, L=128, H=512, E=32, NL=3, IN0=161 (pad 192)
#define BB 256
#define TT 128
#define HH 512
#define G3 1536

typedef __attribute__((ext_vector_type(8))) short bf16x8;
typedef __attribute__((ext_vector_type(4))) float f32x4;

__device__ __forceinline__ unsigned short f2bf(float f){
  unsigned int x = __builtin_bit_cast(unsigned int, f);
  x = x + 0x7fffu + ((x >> 16) & 1u);
  return (unsigned short)(x >> 16);
}
__device__ __forceinline__ float bf2f(unsigned short u){
  unsigned int x = ((unsigned int)u) << 16;
  return __builtin_bit_cast(float, x);
}
__device__ __forceinline__ void gl_lds16(const void* g, void* l){
  __builtin_amdgcn_global_load_lds((const __attribute__((address_space(1))) unsigned int*)g,
                                   (__attribute__((address_space(3))) unsigned int*)l, 16, 0, 0);
}

// ---- prep: convert five [1536][512] f32 weights to bf16 (Whh0..2, Wih1, Wih2)
__global__ __launch_bounds__(256) void kconv5(
    const float* __restrict__ a0, const float* __restrict__ a1, const float* __restrict__ a2,
    const float* __restrict__ a3, const float* __restrict__ a4,
    unsigned short* __restrict__ d0, unsigned short* __restrict__ d1, unsigned short* __restrict__ d2,
    unsigned short* __restrict__ d3, unsigned short* __restrict__ d4){
  int i = blockIdx.x*256 + threadIdx.x;   // grid 3072*256 = 786432 exactly
  d0[i] = f2bf(a0[i]); d1[i] = f2bf(a1[i]); d2[i] = f2bf(a2[i]);
  d3[i] = f2bf(a3[i]); d4[i] = f2bf(a4[i]);
}

// ---- prep: Wih0 pad 161->192 to bf16; fc_W transpose to [512][64] f32
__global__ __launch_bounds__(256) void kmisc(const float* __restrict__ wih0,
    unsigned short* __restrict__ wih0p, const float* __restrict__ fcw,
    float* __restrict__ fcwt){
  int i = blockIdx.x*256 + threadIdx.x;  // grid 1152*256 = 294912
  if (i < 1536*192){
    int n = i / 192, k = i - n*192;
    wih0p[i] = (k < 161) ? f2bf(wih0[n*161 + k]) : (unsigned short)0;
  }
  if (i < 512*64){
    int k = i >> 6, v = i & 63;
    fcwt[i] = fcw[v*512 + k];
  }
}

// ---- prep: build x0 [32768][192] bf16 (latent | shifted-embed | enthalpy | zeros)
__global__ __launch_bounds__(192) void kx0(const float* __restrict__ latent,
    const float* __restrict__ enth, const int* __restrict__ inp,
    const float* __restrict__ emb, unsigned short* __restrict__ x0){
  int c = threadIdx.x;
  #pragma unroll
  for (int mr = 0; mr < 4; ++mr){
    int m = blockIdx.x*4 + mr;       // grid 8192 -> m < 32768
    int b = m >> 7, t = m & 127;
    float v;
    if (c < 128) v = latent[b*128 + c];
    else if (c < 160){
      int tok = (t == 0) ? 0 : inp[b*128 + t - 1];
      v = emb[tok*32 + (c - 128)];
    }
    else if (c == 160) v = enth[b];
    else v = 0.f;
    x0[(size_t)m*192 + c] = f2bf(v);
  }
}

// ---- bf16 MFMA GEMM: C[m][n] = A[m][K] @ Bt[n][K]^T + bias[n]; bf16 out; M by grid
__global__ __launch_bounds__(256) void kgemm(const unsigned short* __restrict__ A,
    const unsigned short* __restrict__ Bt, const float* __restrict__ bias,
    unsigned short* __restrict__ C, int K){
  __shared__ __align__(16) unsigned short As[128*32];
  __shared__ __align__(16) unsigned short Bs[128*32];
  const int m0 = blockIdx.y*128, n0 = blockIdx.x*128;
  const int wv = threadIdx.x >> 6, lane = threadIdx.x & 63;
  const int woffM = (wv >> 1)*64, woffN = (wv & 1)*64;
  f32x4 acc[4][4] = {};
  for (int k0 = 0; k0 < K; k0 += 32){
    __syncthreads();
    #pragma unroll
    for (int i = 0; i < 4; ++i){
      int e = wv*4 + i;
      int ee = e & 7;
      int row = ee*16 + (lane >> 2);
      if (e < 8) gl_lds16(A  + (size_t)(m0+row)*K + k0 + (lane & 3)*8, (void*)&As[ee*512]);
      else       gl_lds16(Bt + (size_t)(n0+row)*K + k0 + (lane & 3)*8, (void*)&Bs[ee*512]);
    }
    __syncthreads();
    bf16x8 af[4], bf_[4];
    #pragma unroll
    for (int mt = 0; mt < 4; ++mt)
      af[mt] = *(const bf16x8*)&As[(woffM + mt*16 + (lane & 15))*32 + (lane >> 4)*8];
    #pragma unroll
    for (int nt = 0; nt < 4; ++nt)
      bf_[nt] = *(const bf16x8*)&Bs[(woffN + nt*16 + (lane & 15))*32 + (lane >> 4)*8];
    #pragma unroll
    for (int mt = 0; mt < 4; ++mt)
      #pragma unroll
      for (int nt = 0; nt < 4; ++nt)
        acc[mt][nt] = __builtin_amdgcn_mfma_f32_16x16x32_bf16(af[mt], bf_[nt], acc[mt][nt], 0, 0, 0);
  }
  const int col = lane & 15, lq = lane >> 4;
  #pragma unroll
  for (int nt = 0; nt < 4; ++nt){
    float bv = bias[n0 + woffN + nt*16 + col];
    #pragma unroll
    for (int mt = 0; mt < 4; ++mt)
      #pragma unroll
      for (int r = 0; r < 4; ++r){
        int grow = m0 + woffM + mt*16 + lq*4 + r;
        int gcol = n0 + woffN + nt*16 + col;
        C[(size_t)grow*G3 + gcol] = f2bf(acc[mt][nt][r] + bv);
      }
  }
}

// ---- persistent GRU layer: ZERO cross-block communication, registers sized to fit.
// 16 blocks (16 batch rows each) x 1024 threads (16 waves). Wave w owns h-cols
// w*32..+31 for ALL 3 gates: Whh slice resident in VGPRs (384/lane; total block
// budget 384+acc24+gin8+ho8+misc ~455 < 480 spill cliff — R7's mt=2 hit ~500 and
// collapsed to VGPR_Count=64 full-scratch). h double-buffered in LDS (2x16KB,
// XOR-swizzled); ONE barrier per step; gates fully in-lane.
template<int STORE_BF, int STORE_F>
__global__ __launch_bounds__(1024, 1) void kgru(
    const unsigned short* __restrict__ Wb, const float* __restrict__ bhh,
    const unsigned short* __restrict__ gi,
    unsigned short* __restrict__ xo_bf, float* __restrict__ xo_f){
  const int b0 = blockIdx.x * 16;
  const int w = threadIdx.x >> 6, lane = threadIdx.x & 63;
  const int c = lane & 15, lq = lane >> 4;
  __shared__ __align__(16) unsigned short hs[2][16*512];   // 32KB double-buffered h

  // resident Whh fragments (B-operand: col=c -> gate-row w*32+hf*16+c, k=ks*32+lq*8)
  bf16x8 wf[3][2][16];
  #pragma unroll
  for (int g = 0; g < 3; ++g)
    #pragma unroll
    for (int hf = 0; hf < 2; ++hf){
      const unsigned short* base = Wb + ((size_t)(g*512 + w*32 + hf*16 + c))*512 + lq*8;
      #pragma unroll
      for (int ks = 0; ks < 16; ++ks)
        wf[g][hf][ks] = *(const bf16x8*)(base + ks*32);
    }
  float bias[3][2];
  #pragma unroll
  for (int g = 0; g < 3; ++g)
    #pragma unroll
    for (int hf = 0; hf < 2; ++hf)
      bias[g][hf] = bhh[g*512 + w*32 + hf*16 + c];
  float h_old[2][4];
  #pragma unroll
  for (int hf = 0; hf < 2; ++hf)
    #pragma unroll
    for (int r = 0; r < 4; ++r) h_old[hf][r] = 0.f;

  // running gi row pointers (advance by G3 per step; offsets hf*16/+512/+1024 fold to imm)
  const unsigned short* gp[4];
  #pragma unroll
  for (int r = 0; r < 4; ++r)
    gp[r] = gi + ((size_t)(b0 + lq*4 + r)*TT)*G3 + w*32 + c;

  #pragma unroll 1
  for (int t = 0; t < TT; ++t){
    f32x4 acc[3][2];
    f32x4 gin_[2];
    #pragma unroll
    for (int r = 0; r < 4; ++r)
      #pragma unroll
      for (int hf = 0; hf < 2; ++hf){
        float vr = bf2f(gp[r][hf*16]);
        float vz = bf2f(gp[r][hf*16 + 512]);
        float vn = bf2f(gp[r][hf*16 + 1024]);
        acc[0][hf][r] = vr + bias[0][hf];
        acc[1][hf][r] = vz + bias[1][hf];
        acc[2][hf][r] = bias[2][hf];
        gin_[hf][r] = vn;
      }
    if (t > 0){
      const char* hsr = (const char*)hs[(t - 1) & 1];
      #pragma unroll
      for (int ks = 0; ks < 16; ++ks){
        bf16x8 af = *(const bf16x8*)(hsr + c*1024 + (((ks*4 + lq) ^ (c & 7)) << 4));
        #pragma unroll
        for (int g = 0; g < 3; ++g)
          #pragma unroll
          for (int hf = 0; hf < 2; ++hf)
            acc[g][hf] = __builtin_amdgcn_mfma_f32_16x16x32_bf16(af, wf[g][hf][ks], acc[g][hf], 0, 0, 0);
      }
    }
    // gates (fully in-lane) + publish to hs[t&1] + xo stream
    char* hsw = (char*)hs[t & 1];
    #pragma unroll
    for (int hf = 0; hf < 2; ++hf)
      #pragma unroll
      for (int r = 0; r < 4; ++r){
        float rr = 1.f/(1.f + __expf(-acc[0][hf][r]));
        float zz = 1.f/(1.f + __expf(-acc[1][hf][r]));
        float np = gin_[hf][r] + rr*acc[2][hf][r];
        float e2 = __expf(2.f*np);
        float nn = 1.f - 2.f/(e2 + 1.f);
        float hn = (1.f - zz)*nn + zz*h_old[hf][r];
        h_old[hf][r] = hn;
        unsigned short hv = f2bf(hn);
        int row = lq*4 + r;
        int j = w*32 + hf*16 + c;
        *(unsigned short*)(hsw + row*1024 + ((((j >> 3) ^ (row & 7))) << 4) + (j & 7)*2) = hv;
        if (STORE_BF) xo_bf[((size_t)(b0 + row)*TT + t)*512 + j] = hv;
        if (STORE_F)  xo_f [((size_t)(b0 + row)*TT + t)*512 + j] = hn;
      }
    #pragma unroll
    for (int r = 0; r < 4; ++r) gp[r] += G3;
    __syncthreads();
  }
}

// ---- final FC in f32 (precision): logits[m][64] = x[m][512] @ fcwt + fc_b
__global__ __launch_bounds__(256) void kfc(const float* __restrict__ x,
    const float* __restrict__ wt, const float* __restrict__ fcb, float* __restrict__ out){
  __shared__ __align__(16) float xs[16*512];
  const int m0 = blockIdx.x*16;   // grid 2048
  for (int c = threadIdx.x; c < 2048; c += 256){
    int row = c >> 7, o = c & 127;
    *(f32x4*)&xs[row*512 + o*4] = *(const f32x4*)(x + (size_t)(m0+row)*512 + o*4);
  }
  __syncthreads();
  const int colv = threadIdx.x & 63, rq = threadIdx.x >> 6;
  float a0 = 0.f, a1 = 0.f, a2 = 0.f, a3 = 0.f;
  const float* x0p = xs + (rq*4 + 0)*512;
  const float* x1p = xs + (rq*4 + 1)*512;
  const float* x2p = xs + (rq*4 + 2)*512;
  const float* x3p = xs + (rq*4 + 3)*512;
  #pragma unroll 8
  for (int k = 0; k < 512; ++k){
    float w = wt[k*64 + colv];
    a0 += w * x0p[k]; a1 += w * x1p[k]; a2 += w * x2p[k]; a3 += w * x3p[k];
  }
  float bv = fcb[colv];
  out[(size_t)(m0 + rq*4 + 0)*64 + colv] = a0 + bv;
  out[(size_t)(m0 + rq*4 + 1)*64 + colv] = a1 + bv;
  out[(size_t)(m0 + rq*4 + 2)*64 + colv] = a2 + bv;
  out[(size_t)(m0 + rq*4 + 3)*64 + colv] = a3 + bv;
}

extern "C" void kernel_launch(void* const* d_in, const int* in_sizes, int n_in,
                              void* d_out, int out_size, void* d_ws, size_t ws_size,
                              hipStream_t stream){
  const float* latent = (const float*)d_in[0];
  const float* enth   = (const float*)d_in[1];
  const int*   inp    = (const int*)d_in[2];
  const float* emb    = (const float*)d_in[3];
  const float* Wih0   = (const float*)d_in[4];
  const float* Whh0   = (const float*)d_in[5];
  const float* bih0   = (const float*)d_in[6];
  const float* bhh0   = (const float*)d_in[7];
  const float* Wih1   = (const float*)d_in[8];
  const float* Whh1   = (const float*)d_in[9];
  const float* bih1   = (const float*)d_in[10];
  const float* bhh1   = (const float*)d_in[11];
  const float* Wih2   = (const float*)d_in[12];
  const float* Whh2   = (const float*)d_in[13];
  const float* bih2   = (const float*)d_in[14];
  const float* bhh2   = (const float*)d_in[15];
  const float* fcW    = (const float*)d_in[16];
  const float* fcb    = (const float*)d_in[17];

  char* ws = (char*)d_ws;
  constexpr size_t OFF_X0   = 4096;
  constexpr size_t OFF_XA   = OFF_X0   + (size_t)32768*192*2;
  constexpr size_t OFF_XB   = OFF_XA   + (size_t)32768*512*2;
  constexpr size_t OFF_X2F  = OFF_XB   + (size_t)32768*512*2;
  constexpr size_t OFF_WHH  = OFF_X2F  + (size_t)32768*512*4;
  constexpr size_t OFF_WIH0 = OFF_WHH  + (size_t)3*1536*512*2;
  constexpr size_t OFF_WIH1 = OFF_WIH0 + (size_t)1536*192*2;
  constexpr size_t OFF_WIH2 = OFF_WIH1 + (size_t)1536*512*2;
  constexpr size_t OFF_FCWT = OFF_WIH2 + (size_t)1536*512*2;
  constexpr size_t OFF_GI   = OFF_FCWT + (size_t)512*64*4;

  unsigned short* x0    = (unsigned short*)(ws + OFF_X0);
  unsigned short* xa    = (unsigned short*)(ws + OFF_XA);
  unsigned short* xb    = (unsigned short*)(ws + OFF_XB);
  float* x2f            = (float*)(ws + OFF_X2F);
  unsigned short* whb0  = (unsigned short*)(ws + OFF_WHH);
  unsigned short* whb1  = whb0 + (size_t)1536*512;
  unsigned short* whb2  = whb1 + (size_t)1536*512;
  unsigned short* wih0p = (unsigned short*)(ws + OFF_WIH0);
  unsigned short* wih1b = (unsigned short*)(ws + OFF_WIH1);
  unsigned short* wih2b = (unsigned short*)(ws + OFF_WIH2);
  float* fcwt           = (float*)(ws + OFF_FCWT);
  unsigned short* gi    = (unsigned short*)(ws + OFF_GI);   // always bf16

  kconv5<<<3072, 256, 0, stream>>>(Whh0, Whh1, Whh2, Wih1, Wih2, whb0, whb1, whb2, wih1b, wih2b);
  kmisc <<<1152, 256, 0, stream>>>(Wih0, wih0p, fcW, fcwt);
  kx0   <<<8192, 192, 0, stream>>>(latent, enth, inp, emb, x0);

  kgemm<<<dim3(12,256), 256, 0, stream>>>(x0, wih0p, bih0, gi, 192);
  kgru<1,0><<<16, 1024, 0, stream>>>(whb0, bhh0, gi, xa, x2f);
  kgemm<<<dim3(12,256), 256, 0, stream>>>(xa, wih1b, bih1, gi, 512);
  kgru<1,0><<<16, 1024, 0, stream>>>(whb1, bhh1, gi, xb, x2f);
  kgemm<<<dim3(12,256), 256, 0, stream>>>(xb, wih2b, bih2, gi, 512);
  kgru<0,1><<<16, 1024, 0, stream>>>(whb2, bhh2, gi, xa, x2f);
  kfc  <<<2048, 256, 0, stream>>>(x2f, fcwt, fcb, (float*)d_out);
}

// Round 10
// 2217.769 us; speedup vs baseline: 9.9366x; 7.5760x over previous
//
#include <hip/hip_runtime.h>
#include <stdint.h>

// CondDecoder: B=256, T=128, V=64, L=128, H=512, E=32, NL=3, IN0=161 (pad 192)
#define TT 128
#define G3 1536

typedef __attribute__((ext_vector_type(8))) short bf16x8;
typedef __attribute__((ext_vector_type(4))) float f32x4;

__device__ __forceinline__ unsigned short f2bf(float f){
  unsigned int x = __builtin_bit_cast(unsigned int, f);
  x = x + 0x7fffu + ((x >> 16) & 1u);
  return (unsigned short)(x >> 16);
}
__device__ __forceinline__ float bf2f(unsigned short u){
  unsigned int x = ((unsigned int)u) << 16;
  return __builtin_bit_cast(float, x);
}
__device__ __forceinline__ void gl_lds16(const void* g, void* l){
  __builtin_amdgcn_global_load_lds((const __attribute__((address_space(1))) unsigned int*)g,
                                   (__attribute__((address_space(3))) unsigned int*)l, 16, 0, 0);
}

// ---- prep: Wih1, Wih2 f32 -> bf16 flat
__global__ __launch_bounds__(256) void kconv2(const float* __restrict__ a0,
    const float* __restrict__ a1, unsigned short* __restrict__ d0,
    unsigned short* __restrict__ d1){
  int i = blockIdx.x*256 + threadIdx.x;   // grid 3072*256 = 786432
  d0[i] = f2bf(a0[i]); d1[i] = f2bf(a1[i]);
}

// ---- prep: Whh -> fragment-permuted bf16 so kgru weight loads are coalesced.
// dst i = (((wblk*3+g)*16+ks)*64+lane)*8+e ; wblk=cb*8+w owns cols wblk*16..+15
__global__ __launch_bounds__(256) void kwperm(const float* __restrict__ wsrc,
    unsigned short* __restrict__ o){
  int i = blockIdx.x*256 + threadIdx.x;   // grid 3072
  int e = i & 7, lane = (i >> 3) & 63, ks = (i >> 9) & 15, rem = i >> 13;
  int g = rem % 3, wblk = rem / 3;
  int gcol = wblk*16 + (lane & 15);
  int k = ks*32 + (lane >> 4)*8 + e;
  o[i] = f2bf(wsrc[(size_t)(g*512 + gcol)*512 + k]);
}

// ---- prep: Wih0 pad 161->192 to bf16; fc_W transpose to [512][64] f32
__global__ __launch_bounds__(256) void kmisc(const float* __restrict__ wih0,
    unsigned short* __restrict__ wih0p, const float* __restrict__ fcw,
    float* __restrict__ fcwt){
  int i = blockIdx.x*256 + threadIdx.x;  // grid 1152
  if (i < 1536*192){
    int n = i / 192, k = i - n*192;
    wih0p[i] = (k < 161) ? f2bf(wih0[n*161 + k]) : (unsigned short)0;
  }
  if (i < 512*64){
    int k = i >> 6, v = i & 63;
    fcwt[i] = fcw[v*512 + k];
  }
}

// ---- prep: build x0 [32768][192] bf16 (latent | shifted-embed | enthalpy | zeros)
__global__ __launch_bounds__(192) void kx0(const float* __restrict__ latent,
    const float* __restrict__ enth, const int* __restrict__ inp,
    const float* __restrict__ emb, unsigned short* __restrict__ x0){
  int c = threadIdx.x;
  #pragma unroll
  for (int mr = 0; mr < 4; ++mr){
    int m = blockIdx.x*4 + mr;       // grid 8192
    int b = m >> 7, t = m & 127;
    float v;
    if (c < 128) v = latent[b*128 + c];
    else if (c < 160){
      int tok = (t == 0) ? 0 : inp[b*128 + t - 1];
      v = emb[tok*32 + (c - 128)];
    }
    else if (c == 160) v = enth[b];
    else v = 0.f;
    x0[(size_t)m*192 + c] = f2bf(v);
  }
}

// ---- bf16 MFMA GEMM: C[m][n] = A[m][K] @ Bt[n][K]^T + bias[n]; bf16 out
__global__ __launch_bounds__(256) void kgemm(const unsigned short* __restrict__ A,
    const unsigned short* __restrict__ Bt, const float* __restrict__ bias,
    unsigned short* __restrict__ C, int K){
  __shared__ __align__(16) unsigned short As[128*32];
  __shared__ __align__(16) unsigned short Bs[128*32];
  const int m0 = blockIdx.y*128, n0 = blockIdx.x*128;
  const int wv = threadIdx.x >> 6, lane = threadIdx.x & 63;
  const int woffM = (wv >> 1)*64, woffN = (wv & 1)*64;
  f32x4 acc[4][4] = {};
  for (int k0 = 0; k0 < K; k0 += 32){
    __syncthreads();
    #pragma unroll
    for (int i = 0; i < 4; ++i){
      int e = wv*4 + i;
      int ee = e & 7;
      int row = ee*16 + (lane >> 2);
      if (e < 8) gl_lds16(A  + (size_t)(m0+row)*K + k0 + (lane & 3)*8, (void*)&As[ee*512]);
      else       gl_lds16(Bt + (size_t)(n0+row)*K + k0 + (lane & 3)*8, (void*)&Bs[ee*512]);
    }
    __syncthreads();
    bf16x8 af[4], bf_[4];
    #pragma unroll
    for (int mt = 0; mt < 4; ++mt)
      af[mt] = *(const bf16x8*)&As[(woffM + mt*16 + (lane & 15))*32 + (lane >> 4)*8];
    #pragma unroll
    for (int nt = 0; nt < 4; ++nt)
      bf_[nt] = *(const bf16x8*)&Bs[(woffN + nt*16 + (lane & 15))*32 + (lane >> 4)*8];
    #pragma unroll
    for (int mt = 0; mt < 4; ++mt)
      #pragma unroll
      for (int nt = 0; nt < 4; ++nt)
        acc[mt][nt] = __builtin_amdgcn_mfma_f32_16x16x32_bf16(af[mt], bf_[nt], acc[mt][nt], 0, 0, 0);
  }
  const int col = lane & 15, lq = lane >> 4;
  #pragma unroll
  for (int nt = 0; nt < 4; ++nt){
    float bv = bias[n0 + woffN + nt*16 + col];
    #pragma unroll
    for (int mt = 0; mt < 4; ++mt)
      #pragma unroll
      for (int r = 0; r < 4; ++r){
        int grow = m0 + woffM + mt*16 + lq*4 + r;
        int gcol = n0 + woffN + nt*16 + col;
        C[(size_t)grow*G3 + gcol] = f2bf(acc[mt][nt][r] + bv);
      }
  }
}

// ---- GRU layer: 64 blocks = 16 rowgroups(16 rows) x 4 colblocks(128 cols x 3 gates).
// 512 threads (8 waves, 256-VGPR cap): Whh slice resident (192 VGPR/lane).
// h exchange via PROVEN MALL protocol (R3/R6): ALL cross-block data moves through
// __hip_atomic_* relaxed-agent ops. R5 (sc1 NaN) + R9 (sc0 deadlock) prove raw
// cache-bit asm is NOT a coherence substitute. Per-WAVE flags (32/rowgroup):
// publish = wave-local hpub shuffle -> 1x8B atomic store/lane -> per-wave vmcnt(0)
// -> wave flag. One __syncthreads per step (staging barrier). Double-buffer safety:
// flag>=t+2 implies that wave's t+1 pull completed (program order) -> no WAR race.
template<int STORE_BF, int STORE_F>
__global__ __launch_bounds__(512, 1) void kgru(
    const unsigned short* __restrict__ Wp, const float* __restrict__ bhh,
    const unsigned short* __restrict__ gi,
    unsigned short* __restrict__ hb,          // [16rg][2][16][512] bf16
    unsigned short* __restrict__ xo_bf, float* __restrict__ xo_f,
    int* __restrict__ flags){
  const int bid = blockIdx.x;
  const int rg = bid & 15, cb = bid >> 4;
  const int b0 = rg*16;
  const int tid = threadIdx.x;
  const int w = tid >> 6, lane = tid & 63;
  const int c = lane & 15, lq = lane >> 4;
  const int gcol = cb*128 + w*16 + c;
  __shared__ __align__(16) unsigned short hs[2][16*512];   // 32KB staging
  __shared__ __align__(16) unsigned short hpub[8][256];    // 4KB wave-local shuffle

  // resident weight fragments (coalesced; pre-permuted by kwperm): 192 VGPR
  const unsigned short* wbase = Wp + (size_t)(cb*8 + w)*24576 + lane*8;
  bf16x8 wf[3][16];
  #pragma unroll
  for (int g = 0; g < 3; ++g)
    #pragma unroll
    for (int ks = 0; ks < 16; ++ks)
      wf[g][ks] = *(const bf16x8*)(wbase + g*8192 + ks*512);
  float bias[3];
  #pragma unroll
  for (int g = 0; g < 3; ++g) bias[g] = bhh[g*512 + gcol];
  float h_old[4] = {0.f, 0.f, 0.f, 0.f};

  unsigned short* hrg = hb + (size_t)rg*16384;   // 2 slots x 8192 elems
  int* myf = flags + rg*32;                      // 32 per-wave slots (cb*8+w)
  const unsigned short* gbase = gi + ((size_t)(b0 + lq*4)*TT)*G3 + gcol;

  #pragma unroll 1
  for (int t = 0; t < TT; ++t){
    // gate-input loads (latency hidden under poll/pull)
    f32x4 acc[3]; f32x4 gin;
    #pragma unroll
    for (int r = 0; r < 4; ++r){
      const unsigned short* p = gbase + (size_t)r*TT*G3;
      acc[0][r] = bf2f(p[0])    + bias[0];
      acc[1][r] = bf2f(p[512])  + bias[1];
      acc[2][r] = bias[2];
      gin[r]    = bf2f(p[1024]);
    }
    gbase += G3;
    if (t > 0){
      // poll the 32 per-wave flags of this rowgroup (atomic loads, no fences)
      while (true){
        int f = __hip_atomic_load(myf + (lane & 31), __ATOMIC_RELAXED, __HIP_MEMORY_SCOPE_AGENT);
        if (__all(f >= t)) break;
        __builtin_amdgcn_s_sleep(1);
      }
      // pull 16KB (2048 qwords, 4/thread) via 8B atomic loads -> swizzled LDS
      const unsigned long long* src8 = (const unsigned long long*)(hrg + (t & 1)*8192);
      unsigned long long pv[4];
      #pragma unroll
      for (int j = 0; j < 4; ++j)
        pv[j] = __hip_atomic_load(src8 + tid + j*512, __ATOMIC_RELAXED, __HIP_MEMORY_SCOPE_AGENT);
      char* hsw = (char*)hs[t & 1];
      #pragma unroll
      for (int j = 0; j < 4; ++j){
        int idx = tid + j*512;
        int row = idx >> 7, q = idx & 127;
        *(unsigned long long*)(hsw + row*1024 + (((q >> 1) ^ (row & 7)) << 4)
                               + ((q & 1) << 3)) = pv[j];
      }
    }
    __syncthreads();                               // staging barrier (only one/step)
    if (t > 0){
      const char* hsr = (const char*)hs[t & 1];
      #pragma unroll
      for (int ks = 0; ks < 16; ++ks){
        bf16x8 af = *(const bf16x8*)(hsr + c*1024 + (((ks*4 + lq) ^ (c & 7)) << 4));
        acc[0] = __builtin_amdgcn_mfma_f32_16x16x32_bf16(af, wf[0][ks], acc[0], 0, 0, 0);
        acc[1] = __builtin_amdgcn_mfma_f32_16x16x32_bf16(af, wf[1][ks], acc[1], 0, 0, 0);
        acc[2] = __builtin_amdgcn_mfma_f32_16x16x32_bf16(af, wf[2][ks], acc[2], 0, 0, 0);
      }
    }
    // gates (fully in-lane)
    unsigned short hv[4]; float hf[4];
    #pragma unroll
    for (int r = 0; r < 4; ++r){
      float rr = 1.f/(1.f + __expf(-acc[0][r]));
      float zz = 1.f/(1.f + __expf(-acc[1][r]));
      float np = gin[r] + rr*acc[2][r];
      float ee = __expf(2.f*np);
      float nn = 1.f - 2.f/(ee + 1.f);
      float hn = (1.f - zz)*nn + zz*h_old[r];
      h_old[r] = hn; hf[r] = hn; hv[r] = f2bf(hn);
    }
    // wave-local publish shuffle: hpub[w] is 16 rows x 16 cols (this wave's slice)
    #pragma unroll
    for (int r = 0; r < 4; ++r)
      hpub[w][(lq*4 + r)*16 + c] = hv[r];
    __builtin_amdgcn_sched_barrier(0);             // order LDS write -> read (in-wave)
    // 1 qword/lane: row = lane>>2, cols (lane&3)*4..+3 of this wave's 16-col slice
    unsigned long long pub = *(const unsigned long long*)&hpub[w][(lane >> 2)*16 + (lane & 3)*4];
    unsigned long long* dst8 = (unsigned long long*)(hrg + ((t + 1) & 1)*8192);
    __hip_atomic_store(dst8 + (lane >> 2)*128 + cb*32 + w*4 + (lane & 3), pub,
                       __ATOMIC_RELAXED, __HIP_MEMORY_SCOPE_AGENT);
    asm volatile("s_waitcnt vmcnt(0)" ::: "memory");   // this wave's h at MALL
    if (lane == 0)
      __hip_atomic_store(myf + (cb*8 + w), t + 1, __ATOMIC_RELAXED, __HIP_MEMORY_SCOPE_AGENT);
    __builtin_amdgcn_sched_barrier(0);             // xo strictly after flag
    if (STORE_BF){
      #pragma unroll
      for (int r = 0; r < 4; ++r)
        xo_bf[((size_t)(b0 + lq*4 + r)*TT + t)*512 + gcol] = hv[r];
    }
    if (STORE_F){
      #pragma unroll
      for (int r = 0; r < 4; ++r)
        xo_f[((size_t)(b0 + lq*4 + r)*TT + t)*512 + gcol] = hf[r];
    }
  }
}

// ---- final FC in f32 (precision): logits[m][64] = x[m][512] @ fcwt + fc_b
__global__ __launch_bounds__(256) void kfc(const float* __restrict__ x,
    const float* __restrict__ wt, const float* __restrict__ fcb, float* __restrict__ out){
  __shared__ __align__(16) float xs[16*512];
  const int m0 = blockIdx.x*16;   // grid 2048
  for (int c = threadIdx.x; c < 2048; c += 256){
    int row = c >> 7, o = c & 127;
    *(f32x4*)&xs[row*512 + o*4] = *(const f32x4*)(x + (size_t)(m0+row)*512 + o*4);
  }
  __syncthreads();
  const int colv = threadIdx.x & 63, rq = threadIdx.x >> 6;
  float a0 = 0.f, a1 = 0.f, a2 = 0.f, a3 = 0.f;
  const float* x0p = xs + (rq*4 + 0)*512;
  const float* x1p = xs + (rq*4 + 1)*512;
  const float* x2p = xs + (rq*4 + 2)*512;
  const float* x3p = xs + (rq*4 + 3)*512;
  #pragma unroll 8
  for (int k = 0; k < 512; ++k){
    float w = wt[k*64 + colv];
    a0 += w * x0p[k]; a1 += w * x1p[k]; a2 += w * x2p[k]; a3 += w * x3p[k];
  }
  float bv = fcb[colv];
  out[(size_t)(m0 + rq*4 + 0)*64 + colv] = a0 + bv;
  out[(size_t)(m0 + rq*4 + 1)*64 + colv] = a1 + bv;
  out[(size_t)(m0 + rq*4 + 2)*64 + colv] = a2 + bv;
  out[(size_t)(m0 + rq*4 + 3)*64 + colv] = a3 + bv;
}

extern "C" void kernel_launch(void* const* d_in, const int* in_sizes, int n_in,
                              void* d_out, int out_size, void* d_ws, size_t ws_size,
                              hipStream_t stream){
  const float* latent = (const float*)d_in[0];
  const float* enth   = (const float*)d_in[1];
  const int*   inp    = (const int*)d_in[2];
  const float* emb    = (const float*)d_in[3];
  const float* Wih0   = (const float*)d_in[4];
  const float* Whh0   = (const float*)d_in[5];
  const float* bih0   = (const float*)d_in[6];
  const float* bhh0   = (const float*)d_in[7];
  const float* Wih1   = (const float*)d_in[8];
  const float* Whh1   = (const float*)d_in[9];
  const float* bih1   = (const float*)d_in[10];
  const float* bhh1   = (const float*)d_in[11];
  const float* Wih2   = (const float*)d_in[12];
  const float* Whh2   = (const float*)d_in[13];
  const float* bih2   = (const float*)d_in[14];
  const float* bhh2   = (const float*)d_in[15];
  const float* fcW    = (const float*)d_in[16];
  const float* fcb    = (const float*)d_in[17];

  char* ws = (char*)d_ws;
  constexpr size_t OFF_HB   = 4096;                                  // flags at 0 (2KB)
  constexpr size_t OFF_X0   = OFF_HB   + (size_t)16*2*8192*2;        // 512KB hb
  constexpr size_t OFF_XA   = OFF_X0   + (size_t)32768*192*2;
  constexpr size_t OFF_XB   = OFF_XA   + (size_t)32768*512*2;
  constexpr size_t OFF_X2F  = OFF_XB   + (size_t)32768*512*2;
  constexpr size_t OFF_WHP  = OFF_X2F  + (size_t)32768*512*4;
  constexpr size_t OFF_WIH0 = OFF_WHP  + (size_t)3*1536*512*2;
  constexpr size_t OFF_WIH1 = OFF_WIH0 + (size_t)1536*192*2;
  constexpr size_t OFF_WIH2 = OFF_WIH1 + (size_t)1536*512*2;
  constexpr size_t OFF_FCWT = OFF_WIH2 + (size_t)1536*512*2;
  constexpr size_t OFF_GI   = OFF_FCWT + (size_t)512*64*4;

  int* flags            = (int*)ws;
  unsigned short* hbuf  = (unsigned short*)(ws + OFF_HB);
  unsigned short* x0    = (unsigned short*)(ws + OFF_X0);
  unsigned short* xa    = (unsigned short*)(ws + OFF_XA);
  unsigned short* xb    = (unsigned short*)(ws + OFF_XB);
  float* x2f            = (float*)(ws + OFF_X2F);
  unsigned short* whp0  = (unsigned short*)(ws + OFF_WHP);
  unsigned short* whp1  = whp0 + (size_t)1536*512;
  unsigned short* whp2  = whp1 + (size_t)1536*512;
  unsigned short* wih0p = (unsigned short*)(ws + OFF_WIH0);
  unsigned short* wih1b = (unsigned short*)(ws + OFF_WIH1);
  unsigned short* wih2b = (unsigned short*)(ws + OFF_WIH2);
  float* fcwt           = (float*)(ws + OFF_FCWT);
  unsigned short* gi    = (unsigned short*)(ws + OFF_GI);

  kconv2<<<3072, 256, 0, stream>>>(Wih1, Wih2, wih1b, wih2b);
  kwperm<<<3072, 256, 0, stream>>>(Whh0, whp0);
  kwperm<<<3072, 256, 0, stream>>>(Whh1, whp1);
  kwperm<<<3072, 256, 0, stream>>>(Whh2, whp2);
  kmisc <<<1152, 256, 0, stream>>>(Wih0, wih0p, fcW, fcwt);
  kx0   <<<8192, 192, 0, stream>>>(latent, enth, inp, emb, x0);

  kgemm<<<dim3(12,256), 256, 0, stream>>>(x0, wih0p, bih0, gi, 192);
  (void)hipMemsetAsync(flags, 0, 2048, stream);
  kgru<1,0><<<64, 512, 0, stream>>>(whp0, bhh0, gi, hbuf, xa, x2f, flags);
  kgemm<<<dim3(12,256), 256, 0, stream>>>(xa, wih1b, bih1, gi, 512);
  (void)hipMemsetAsync(flags, 0, 2048, stream);
  kgru<1,0><<<64, 512, 0, stream>>>(whp1, bhh1, gi, hbuf, xb, x2f, flags);
  kgemm<<<dim3(12,256), 256, 0, stream>>>(xb, wih2b, bih2, gi, 512);
  (void)hipMemsetAsync(flags, 0, 2048, stream);
  kgru<0,1><<<64, 512, 0, stream>>>(whp2, bhh2, gi, hbuf, xa, x2f, flags);
  kfc  <<<2048, 256, 0, stream>>>(x2f, fcwt, fcb, (float*)d_out);
}